// Round 6
// baseline (155.201 us; speedup 1.0000x reference)
//
#include <hip/hip_runtime.h>

// MultiboxLoss anchor matching: B=64, T=100, A=8732, NUM_CLASSES=21
// out = [loc (B,A,4) f32][conf (B,A) as f32]
// Round 6: split into two reduction-free passes (IoU computed twice, but
// each pass ~0.8 cyc/IoU issue vs 2.3 measured for fused+per-t reduction):
//   P: precompute anchor point-form + target areas; zero keys
//   A: thread=anchor, loop t (uniform loads)  -> per-anchor argmax + encode
//   B: lane=target, serial anchor-chunk scan  -> per-target argmax -> keys
//   F: fixup <=100 overridden anchors/batch (last-t-wins)
// Division: Markstein sequence (rcp + NR + fma residual correction) —
// correctly rounded for normal operands (~18 issue-cyc vs ~40 for IEEE
// microcode). Tripwire: absmax must stay ~0.125, else revert.
//   ws: [0,51200)        u64 keys[B*T]
//       [51200,190912)   float4 apt4[A]   (ax1,ay1,ax2,ay2)
//       [190912,225840)  float aarea[A]
//       [225840,430640)  float4 tpt4[B*T*2] ({x1,y1,x2,y2},{area,label,0,0})
#define BB 64
#define TT 100
#define AA 8732
#define BCH 256                           // anchors per B-chunk
#define NBCH ((AA + BCH - 1) / BCH)       // 35 (tail 28, %4==0)

typedef unsigned long long u64;
typedef unsigned int u32;

// Fast correctly-rounded f32 division (Markstein): valid for normal b>0,
// a>=0 (inter==0 -> exact 0). Matches IEEE RN on all normal inputs.
__device__ __forceinline__ float fdiv_fast(float a, float b) {
    float y = __builtin_amdgcn_rcpf(b);
    float e = __fmaf_rn(-b, y, 1.0f);
    y = __fmaf_rn(y, e, y);
    float q = __fmul_rn(a, y);
    float r = __fmaf_rn(-b, q, a);
    return __fmaf_rn(r, y, q);
}

// Bit-exact (vs numpy f32) IoU core: _rn ops block fp-contract fusion.
__device__ __forceinline__ float iou_f(float bx1, float by1, float bx2, float by2, float areab,
                                       float ax1, float ay1, float ax2, float ay2, float areaa) {
    float dx = fmaxf(__fsub_rn(fminf(bx2, ax2), fmaxf(bx1, ax1)), 0.0f);
    float dy = fmaxf(__fsub_rn(fminf(by2, ay2), fmaxf(by1, ay1)), 0.0f);
    float inter = __fmul_rn(dx, dy);
    float uni = __fsub_rn(__fadd_rn(areab, areaa), inter);
    return fdiv_fast(inter, uni);
}

// P: anchor point-form, target box/area/label pack, key zeroing.
__global__ __launch_bounds__(256) void k_prep(const float* __restrict__ targets,
                                              const float* __restrict__ anchors,
                                              u64* __restrict__ keys,
                                              float4* __restrict__ apt4,
                                              float* __restrict__ aarea,
                                              float4* __restrict__ tpt4) {
    int i = blockIdx.x * 256 + threadIdx.x;
    if (i < AA) {
        float4 c = *(const float4*)(anchors + (size_t)i * 4);
        float hx = __fmul_rn(c.z, 0.5f), hy = __fmul_rn(c.w, 0.5f);
        float x1 = __fsub_rn(c.x, hx), y1 = __fsub_rn(c.y, hy);
        float x2 = __fadd_rn(c.x, hx), y2 = __fadd_rn(c.y, hy);
        apt4[i] = make_float4(x1, y1, x2, y2);
        aarea[i] = __fmul_rn(__fsub_rn(x2, x1), __fsub_rn(y2, y1));
    }
    if (i < BB * TT) {
        keys[i] = 0ULL;
        const float* tg = targets + (size_t)i * 5;
        float x1 = tg[0], y1 = tg[1], x2 = tg[2], y2 = tg[3];
        tpt4[2 * i] = make_float4(x1, y1, x2, y2);
        float ar = __fmul_rn(__fsub_rn(x2, x1), __fsub_rn(y2, y1));
        tpt4[2 * i + 1] = make_float4(ar, tg[4], 0.f, 0.f);
    }
}

// A: thread = (b, anchor). Per-anchor argmax over t (strict >, ascending t =
// first-occurrence) + loc/conf encode. No cross-lane ops. t-loads uniform.
__global__ __launch_bounds__(256) void k_anchor(const float* __restrict__ anchors,
                                                const float4* __restrict__ apt4,
                                                const float* __restrict__ aarea,
                                                const float4* __restrict__ tpt4,
                                                float* __restrict__ out) {
    const int b = blockIdx.y;
    const int a = blockIdx.x * 256 + threadIdx.x;
    if (a >= AA) return;

    const float4 ap = apt4[a];
    const float aar = aarea[a];
    const float4* tb = tpt4 + (size_t)b * TT * 2;

    float best = -1.f;
    int gi = 0;
    #pragma unroll 4
    for (int t = 0; t < TT; ++t) {
        float4 box = tb[2 * t];
        float areab = tb[2 * t + 1].x;
        float v = iou_f(box.x, box.y, box.z, box.w, areab, ap.x, ap.y, ap.z, ap.w, aar);
        if (v > best) { best = v; gi = t; }
    }

    float4 m = tb[2 * gi];
    float lab = tb[2 * gi + 1].y;
    float4 anc = *(const float4*)(anchors + (size_t)a * 4);
    float cx = (m.x + m.z) * 0.5f, cy = (m.y + m.w) * 0.5f;
    float w = m.z - m.x, h = m.w - m.y;
    float l0 = (cx - anc.x) / (0.1f * anc.z);
    float l1 = (cy - anc.y) / (0.1f * anc.w);
    float l2 = logf(w / anc.z) / 0.2f;
    float l3 = logf(h / anc.w) / 0.2f;
    size_t base = ((size_t)b * AA + a) * 4;
    *(float4*)(out + base) = make_float4(l0, l1, l2, l3);
    float conf = (best >= 0.5f) ? (float)(int)(lab + 1.0f) : 0.0f;
    out[(size_t)BB * AA * 4 + (size_t)b * AA + a] = conf;
}

// B: block = (b, 256-anchor chunk); 128 threads; lane's t = threadIdx.x.
// Serial scan over chunk anchors (uniform loads, broadcast), per-lane
// (best,argmax) — strict >, ascending a = first-occurrence. One u64
// atomicMax per valid lane. Lanes t>=100 run a dummy box (discarded).
__global__ __launch_bounds__(128) void k_target(const float4* __restrict__ apt4,
                                                const float* __restrict__ aarea,
                                                const float4* __restrict__ tpt4,
                                                u64* __restrict__ keys) {
    const int b = blockIdx.y;
    const int t = threadIdx.x;
    const int a0 = blockIdx.x * BCH;
    const int len = min(BCH, AA - a0);   // 256 or 28 (both %4==0)

    float4 box = make_float4(2.f, 2.f, 3.f, 3.f);  // dummy: inter==0 vs any anchor
    float areab = 1.f;
    if (t < TT) {
        box = tpt4[((size_t)b * TT + t) * 2];
        areab = tpt4[((size_t)b * TT + t) * 2 + 1].x;
    }

    float best = -1.f;
    int ga = a0;
    #pragma unroll 4
    for (int i = 0; i < len; ++i) {
        float4 ap = apt4[a0 + i];        // wave-uniform address (broadcast)
        float aar = aarea[a0 + i];
        float v = iou_f(box.x, box.y, box.z, box.w, areab, ap.x, ap.y, ap.z, ap.w, aar);
        if (v > best) { best = v; ga = a0 + i; }
    }
    if (t < TT) {
        u64 key = (((u64)__float_as_uint(best)) << 32) | (u64)(u32)~(u32)ga;
        atomicMax(&keys[b * TT + t], key);
    }
}

// Fixup: block per batch. Each t's argmax anchor gets gi=t, ov=1.0.
// Duplicate anchors: only largest t writes (last-wins, = .at[].set).
__global__ __launch_bounds__(128) void k_fixup(const float* __restrict__ targets,
                                               const float* __restrict__ anchors,
                                               const u64* __restrict__ keys,
                                               float* __restrict__ out) {
    const int b = blockIdx.x;
    const int t = threadIdx.x;
    __shared__ u32 sh_a[TT];
    if (t < TT) sh_a[t] = ~(u32)(keys[(size_t)b * TT + t] & 0xFFFFFFFFull);
    __syncthreads();
    if (t >= TT) return;
    u32 a = sh_a[t];
    bool last = true;
    for (int t2 = t + 1; t2 < TT; ++t2)
        if (sh_a[t2] == a) last = false;
    if (!last) return;
    const float* tg = targets + ((size_t)b * TT + t) * 5;
    float4 anc = *(const float4*)(anchors + (size_t)a * 4);
    float mx1 = tg[0], my1 = tg[1], mx2 = tg[2], my2 = tg[3];
    float cx = (mx1 + mx2) * 0.5f, cy = (my1 + my2) * 0.5f;
    float w = mx2 - mx1, h = my2 - my1;
    float l0 = (cx - anc.x) / (0.1f * anc.z);
    float l1 = (cy - anc.y) / (0.1f * anc.w);
    float l2 = logf(w / anc.z) / 0.2f;
    float l3 = logf(h / anc.w) / 0.2f;
    size_t base = ((size_t)b * AA + a) * 4;
    *(float4*)(out + base) = make_float4(l0, l1, l2, l3);
    out[(size_t)BB * AA * 4 + (size_t)b * AA + a] = (float)(int)(tg[4] + 1.0f);
}

extern "C" void kernel_launch(void* const* d_in, const int* in_sizes, int n_in,
                              void* d_out, int out_size, void* d_ws, size_t ws_size,
                              hipStream_t stream) {
    const float* targets = (const float*)d_in[0];  // (B,T,5)
    const float* anchors = (const float*)d_in[1];  // (A,4)
    float* out = (float*)d_out;
    char* ws = (char*)d_ws;
    u64* keys    = (u64*)(ws);                     // 6400 x 8   = 51,200
    float4* apt4 = (float4*)(ws + 51200);          // 8732 x 16  -> 190,912
    float* aarea = (float*)(ws + 190912);          // 8732 x 4   -> 225,840
    float4* tpt4 = (float4*)(ws + 225840);         // 12800 x 16 -> 430,640

    k_prep<<<35, 256, 0, stream>>>(targets, anchors, keys, apt4, aarea, tpt4);
    dim3 gA(35, BB);
    k_anchor<<<gA, 256, 0, stream>>>(anchors, apt4, aarea, tpt4, out);
    dim3 gB(NBCH, BB);
    k_target<<<gB, 128, 0, stream>>>(apt4, aarea, tpt4, keys);
    k_fixup<<<BB, 128, 0, stream>>>(targets, anchors, keys, out);
}

// Round 7
// 145.128 us; speedup vs baseline: 1.0694x; 1.0694x over previous
//
#include <hip/hip_runtime.h>

// MultiboxLoss anchor matching: B=64, T=100, A=8732, NUM_CLASSES=21
// out = [loc (B,A,4) f32][conf (B,A) as f32]
// Round 7: TWO kernels total (measured ~10us fixed overhead per launch in
// this harness — R6's 4 kernels paid ~40us). k_main fuses staging + both
// IoU passes over a 256-anchor chunk; k_fixup reduces per-chunk partial
// keys and patches the <=100 overridden anchors per batch.
//   ws: u64 keys2[B][NCH][TT] = 64*35*100*8 = 1,792,000 B (non-atomic)
#define BB 64
#define TT 100
#define AA 8732
#define CH 256
#define NCH ((AA + CH - 1) / CH)   // 35 (tail 28)

typedef unsigned long long u64;
typedef unsigned int u32;

// Fast correctly-rounded f32 division (Markstein) — validated R6 (absmax
// unchanged vs IEEE microcode on this input set).
__device__ __forceinline__ float fdiv_fast(float a, float b) {
    float y = __builtin_amdgcn_rcpf(b);
    float e = __fmaf_rn(-b, y, 1.0f);
    y = __fmaf_rn(y, e, y);
    float q = __fmul_rn(a, y);
    float r = __fmaf_rn(-b, q, a);
    return __fmaf_rn(r, y, q);
}

// Bit-exact (vs numpy f32) IoU core: _rn ops block fp-contract fusion.
__device__ __forceinline__ float iou_f(float bx1, float by1, float bx2, float by2, float areab,
                                       float ax1, float ay1, float ax2, float ay2, float areaa) {
    float dx = fmaxf(__fsub_rn(fminf(bx2, ax2), fmaxf(bx1, ax1)), 0.0f);
    float dy = fmaxf(__fsub_rn(fminf(by2, ay2), fmaxf(by1, ay1)), 0.0f);
    float inter = __fmul_rn(dx, dy);
    float uni = __fsub_rn(__fadd_rn(areab, areaa), inter);
    return fdiv_fast(inter, uni);
}

// block = (chunk, b), 256 threads.
// Pass 1: thread = anchor (argmax over t, strict >, ascending = first-occ)
//         + loc/conf encode, written directly.
// Pass 2: thread = (half, t): lanes scan 128 LDS anchors (wave-uniform
//         address: half is uniform per wave), strict > ascending = first-occ;
//         halves combined (tie -> half0 = smaller anchor via ~a in key);
//         one non-atomic u64 partial per (b,chunk,t).
__global__ __launch_bounds__(256) void k_main(const float* __restrict__ targets,
                                              const float* __restrict__ anchors,
                                              u64* __restrict__ keys2,
                                              float* __restrict__ out) {
    const int b = blockIdx.y;
    const int c0 = blockIdx.x * CH;
    const int tid = threadIdx.x;
    const int len = min(CH, AA - c0);

    __shared__ float4 s_tbox[TT];
    __shared__ float s_tarea[TT];
    __shared__ float s_tlab[TT];
    __shared__ float4 s_apt4[CH];   // ax1,ay1,ax2,ay2
    __shared__ float s_aar[CH];
    __shared__ u64 s_red[TT][2];

    if (tid < TT) {
        const float* tg = targets + ((size_t)b * TT + tid) * 5;
        float x1 = tg[0], y1 = tg[1], x2 = tg[2], y2 = tg[3];
        s_tbox[tid] = make_float4(x1, y1, x2, y2);
        s_tarea[tid] = __fmul_rn(__fsub_rn(x2, x1), __fsub_rn(y2, y1));
        s_tlab[tid] = tg[4];
    }
    const bool av = tid < len;
    float4 anc = make_float4(1.f, 1.f, 1.f, 1.f);
    float ax1 = 0.f, ay1 = 0.f, ax2 = 0.f, ay2 = 0.f, aar = 1.f;
    if (av) {
        anc = *(const float4*)(anchors + (size_t)(c0 + tid) * 4);
        float hx = __fmul_rn(anc.z, 0.5f), hy = __fmul_rn(anc.w, 0.5f);
        ax1 = __fsub_rn(anc.x, hx); ay1 = __fsub_rn(anc.y, hy);
        ax2 = __fadd_rn(anc.x, hx); ay2 = __fadd_rn(anc.y, hy);
        aar = __fmul_rn(__fsub_rn(ax2, ax1), __fsub_rn(ay2, ay1));
        s_apt4[tid] = make_float4(ax1, ay1, ax2, ay2);
        s_aar[tid] = aar;
    }
    __syncthreads();

    // ---- Pass 1: per-anchor argmax over targets + encode ----
    if (av) {
        float best = -1.f;
        int gi = 0;
        #pragma unroll 4
        for (int t = 0; t < TT; ++t) {
            float4 B = s_tbox[t];              // uniform -> broadcast
            float ar = s_tarea[t];
            float v = iou_f(B.x, B.y, B.z, B.w, ar, ax1, ay1, ax2, ay2, aar);
            if (v > best) { best = v; gi = t; }
        }
        float4 m = s_tbox[gi];
        float cx = (m.x + m.z) * 0.5f, cy = (m.y + m.w) * 0.5f;
        float w = m.z - m.x, h = m.w - m.y;
        float l0 = (cx - anc.x) / (0.1f * anc.z);
        float l1 = (cy - anc.y) / (0.1f * anc.w);
        float l2 = logf(w / anc.z) / 0.2f;
        float l3 = logf(h / anc.w) / 0.2f;
        size_t base = ((size_t)b * AA + (c0 + tid)) * 4;
        *(float4*)(out + base) = make_float4(l0, l1, l2, l3);
        float conf = (best >= 0.5f) ? (float)(int)(s_tlab[gi] + 1.0f) : 0.0f;
        out[(size_t)BB * AA * 4 + (size_t)b * AA + (c0 + tid)] = conf;
    }

    // ---- Pass 2: per-target argmax over this chunk's anchors ----
    {
        const int t = tid & 127;
        const int half = tid >> 7;                    // uniform per wave
        const int jn = half ? max(len - 128, 0) : min(len, 128);
        const int base = half * 128;
        float4 B = make_float4(2.f, 2.f, 3.f, 3.f);   // dummy: inter==0 always
        float ar = 1.f;
        if (t < TT) { B = s_tbox[t]; ar = s_tarea[t]; }
        float best = -1.f;
        int ga = 0;
        #pragma unroll 4
        for (int j = 0; j < jn; ++j) {
            float4 ap = s_apt4[base + j];             // uniform -> broadcast
            float aa = s_aar[base + j];
            float v = iou_f(B.x, B.y, B.z, B.w, ar, ap.x, ap.y, ap.z, ap.w, aa);
            if (v > best) { best = v; ga = base + j; }
        }
        u64 key = 0;
        if (jn > 0)
            key = (((u64)__float_as_uint(best)) << 32) | (u64)(u32)~(u32)(c0 + ga);
        if (t < TT) s_red[t][half] = key;
    }
    __syncthreads();

    if (tid < TT) {
        u64 k0 = s_red[tid][0], k1 = s_red[tid][1];
        keys2[((size_t)b * NCH + blockIdx.x) * TT + tid] = k0 > k1 ? k0 : k1;
    }
}

// Fixup: block per batch. Reduce 35 chunk partials per t (u64 max; equal
// keys impossible, equal IoU -> ~a picks smaller anchor = first-occurrence),
// then each t's argmax anchor gets gi=t, ov=1.0; duplicate anchors: only
// largest t writes (last-wins, = .at[].set semantics).
__global__ __launch_bounds__(128) void k_fixup(const float* __restrict__ targets,
                                               const float* __restrict__ anchors,
                                               const u64* __restrict__ keys2,
                                               float* __restrict__ out) {
    const int b = blockIdx.x;
    const int t = threadIdx.x;
    __shared__ u32 sh_a[TT];
    if (t < TT) {
        u64 m = 0;
        for (int c = 0; c < NCH; ++c) {
            u64 k = keys2[((size_t)b * NCH + c) * TT + t];
            if (k > m) m = k;
        }
        sh_a[t] = ~(u32)(m & 0xFFFFFFFFull);
    }
    __syncthreads();
    if (t >= TT) return;
    u32 a = sh_a[t];
    bool last = true;
    for (int t2 = t + 1; t2 < TT; ++t2)
        if (sh_a[t2] == a) last = false;
    if (!last) return;
    const float* tg = targets + ((size_t)b * TT + t) * 5;
    float4 anc = *(const float4*)(anchors + (size_t)a * 4);
    float mx1 = tg[0], my1 = tg[1], mx2 = tg[2], my2 = tg[3];
    float cx = (mx1 + mx2) * 0.5f, cy = (my1 + my2) * 0.5f;
    float w = mx2 - mx1, h = my2 - my1;
    float l0 = (cx - anc.x) / (0.1f * anc.z);
    float l1 = (cy - anc.y) / (0.1f * anc.w);
    float l2 = logf(w / anc.z) / 0.2f;
    float l3 = logf(h / anc.w) / 0.2f;
    size_t base = ((size_t)b * AA + a) * 4;
    *(float4*)(out + base) = make_float4(l0, l1, l2, l3);
    out[(size_t)BB * AA * 4 + (size_t)b * AA + a] = (float)(int)(tg[4] + 1.0f);
}

extern "C" void kernel_launch(void* const* d_in, const int* in_sizes, int n_in,
                              void* d_out, int out_size, void* d_ws, size_t ws_size,
                              hipStream_t stream) {
    const float* targets = (const float*)d_in[0];  // (B,T,5)
    const float* anchors = (const float*)d_in[1];  // (A,4)
    float* out = (float*)d_out;
    u64* keys2 = (u64*)d_ws;                       // 64*35*100*8 = 1.79 MB

    dim3 gM(NCH, BB);
    k_main<<<gM, 256, 0, stream>>>(targets, anchors, keys2, out);
    k_fixup<<<BB, 128, 0, stream>>>(targets, anchors, keys2, out);
}